// Round 17
// baseline (113.449 us; speedup 1.0000x reference)
//
#include <hip/hip_runtime.h>
#include <hip/hip_cooperative_groups.h>
#include <stdint.h>

#define NCLS 80
#define TOPK 200
#define CONF_T 0.05f
#define CONF_BITS 0x3D4CCCCDu  // __float_as_uint(0.05f)
#define CROPF 300.0f
#define NA 49104
#define NB 8
#define NSEL 256
#define MKEYS 4096
#define NGRP (NA / 16)          // 3069 16-anchor groups per image
#define MROW 5                  // mask row stride in u64
#define OUTFLO ((NCLS + 1) * TOPK * 5)   // 81000 floats per image
#define NCHUNK ((NB * NA) / 64)          // 6138 64-anchor chunks
#define BASE13 125542u          // CONF_BITS >> 13
#define NBINS 4512              // covers (0.05, 1.0] in >>13 space
#define NBLKS 256               // cooperative grid = one block per CU
#define C81 5184                // floats per 64-anchor chunk (64*81)

namespace cg = cooperative_groups;

__device__ __forceinline__ void decode_box(const float4 rg, const float4 an,
                                           float& x1, float& y1, float& x2, float& y2) {
    // anchors: (ymin, xmin, ymax, xmax); reg: (dy, dx, dh, dw)
    float yca = (an.x + an.z) * 0.5f;
    float xca = (an.y + an.w) * 0.5f;
    float ha = an.z - an.x;
    float wa = an.w - an.y;
    float w = expf(rg.w) * wa;
    float h = expf(rg.z) * ha;
    float yc = rg.x * ha + yca;
    float xc = rg.y * wa + xca;
    x1 = fmaxf(xc - w * 0.5f, 0.0f) / CROPF;
    y1 = fmaxf(yc - h * 0.5f, 0.0f) / CROPF;
    x2 = fminf(xc + w * 0.5f, CROPF - 1.0f) / CROPF;
    y2 = fminf(yc + h * 0.5f, CROPF - 1.0f) / CROPF;
}

__device__ __forceinline__ float rlf(float v, int l) {
    return __int_as_float(__builtin_amdgcn_readlane(__float_as_int(v), l));
}

// block-wide inclusive SUFFIX scan over 1024 values; result into outarr[t].
__device__ __forceinline__ void suffix_scan_1024(uint32_t v, int t,
                                                 uint32_t* wtot, uint32_t* outarr) {
    uint32_t r = v;
    const int lane = t & 63, w = t >> 6;
    #pragma unroll
    for (int m = 1; m < 64; m <<= 1) {
        uint32_t o = __shfl_down(r, m);
        if (lane + m < 64) r += o;
    }
    if (lane == 0) wtot[w] = r;
    __syncthreads();
    if (t < 16) {
        uint32_t v0 = wtot[t], x = v0;
        #pragma unroll
        for (int m = 1; m < 16; m <<= 1) {
            uint32_t o = __shfl_down(x, m);
            if (t + m < 16) x += o;
        }
        wtot[t] = x - v0;                      // exclusive suffix of wave totals
    }
    __syncthreads();
    outarr[t] = r + wtot[w];
    __syncthreads();
}

struct PhaseB {
    uint64_t s_keys[MKEYS];        // 32KB  alias: hist u32[NBINS]
    uint64_t s_skeys[MKEYS];       // 32KB  alias: csum u32[1024]
    float    s_gm[NGRP + 3];       // 12KB
    uint64_t s_mask[256 * MROW];   // 10KB
    float4   s_boxo[256];
    float4   s_braw[256];
    float    s_areao[256];
    float4   s_keptbox[TOPK];
    uint64_t s_clsmask[NCLS][4];
    uint32_t s_ccount[NCLS];
    uint32_t s_glist[2048];        // 8KB
    uint32_t s_wtot[16];
    uint32_t s_shv[12];
    float    s_bmaxarr[16];
    float    s_offm;
    uint8_t  s_clsl[256];
    uint64_t s_K[4];
};

union SharedU {
    float  stageA[4 * C81];        // 82944B phase-A staging (4 chunks)
    PhaseB b;                      // ~112KB phase-B workspace
};

// Fused cooperative kernel: phase A (all 256 blocks, grid-stride over 6138
// chunks) -> grid.sync() -> phase B (blocks 0..7, r12-validated phase2).
__global__ __launch_bounds__(1024, 1) void fused_kernel(
    const float* __restrict__ conf, const float* __restrict__ reg,
    const float* __restrict__ anch, unsigned long long* __restrict__ key64,
    float4* __restrict__ boxes, float2* __restrict__ gm2,
    float* __restrict__ out)
{
    __shared__ SharedU sh;
    cg::grid_group grid = cg::this_grid();
    const int blk = blockIdx.x, t = threadIdx.x;

    // ---- stripe-zero d_out (162000 float4 over 262144 threads)
    {
        const int gid = blk * 1024 + t;
        constexpr int TOT4 = NB * OUTFLO / 4;
        if (gid < TOT4)
            reinterpret_cast<float4*>(out)[gid] = make_float4(0.f, 0.f, 0.f, 0.f);
    }

    // ================= PHASE A: conf -> key64/boxes/gm2 =================
    for (int k = 0; ; ++k) {
        const int q0 = blk * 4 + k * 1024;     // first chunk this iteration
        if (q0 >= NCHUNK) break;
        const int nch = min(4, NCHUNK - q0);
        // stage nch contiguous chunks (each 5184 floats)
        {
            const float4* src = reinterpret_cast<const float4*>(conf + (size_t)q0 * C81);
            float4* dst = reinterpret_cast<float4*>(sh.stageA);
            const int n4 = nch * (C81 / 4);
            for (int i = t; i < n4; i += 1024) dst[i] = src[i];
        }
        __syncthreads();

        const int j = t >> 8;                  // chunk-within-iteration 0..3
        const bool act = (j < nch);
        const int tid = t & 255;
        const int la = tid >> 2, sub = tid & 3;
        const int chunk = q0 + j;
        const int quad = chunk * 64 + la;      // global anchor b*NA + a
        const float* crow = sh.stageA + j * C81 + la * 81;
        float best = -3.0e38f; int bc = 255;
        if (act) {
            #pragma unroll
            for (int k2 = 0; k2 < 20; ++k2) {  // lane sub: classes 1+sub, +4 each
                int c = 1 + sub + 4 * k2;
                float v = crow[c];
                if (v > best) { best = v; bc = c; }  // strict > : first-index tie
            }
        }
        for (int m = 1; m <= 2; m <<= 1) {
            float ov = __shfl_xor(best, m);
            int oc = __shfl_xor(bc, m);
            if (ov > best || (ov == best && oc < bc)) { best = ov; bc = oc; }
        }
        unsigned long long key = 0ull;
        float bmaxl = 0.0f;
        if (act && sub == 0) {
            int a = quad % NA;
            float s = 1.0f / (1.0f + expf(-best));
            uint32_t ginv = 0x1FFFFu - (uint32_t)a;  // smaller-index tie-break
            key = ((unsigned long long)__float_as_uint(s) << 32)
                | (unsigned long long)((ginv << 7) | (uint32_t)(bc - 1));
            float4 rg = reinterpret_cast<const float4*>(reg)[quad];
            float4 an = reinterpret_cast<const float4*>(anch)[a];
            float x1, y1, x2, y2; decode_box(rg, an, x1, y1, x2, y2);
            boxes[quad] = make_float4(x1, y1, x2, y2);
            bmaxl = fmaxf(fmaxf(x1, y1), fmaxf(x2, y2));
        }
        // compact key stores: lane l<16 takes lane 4l's key (contiguous 128B/wave)
        {
            const int lane = t & 63, wl = (t >> 6) & 3;
            unsigned long long kk = __shfl(key, (lane & 15) * 4);
            if (act && lane < 16)
                key64[(size_t)chunk * 64 + wl * 16 + lane] = kk;
        }
        float wbest = best;                    // group max logit (monotone)
        #pragma unroll
        for (int m = 1; m < 64; m <<= 1) {
            wbest = fmaxf(wbest, __shfl_xor(wbest, m));
            bmaxl = fmaxf(bmaxl, __shfl_xor(bmaxl, m));
        }
        if (act && (t & 63) == 0)
            gm2[chunk * 4 + ((t >> 6) & 3)] =
                make_float2(1.0f / (1.0f + expf(-wbest)), bmaxl);
        __syncthreads();                       // before next stage overwrite
    }

    grid.sync();                               // all phase-A writes visible

    // ================= PHASE B (blocks 0..7): r12-validated =================
    if (blk >= NB) return;
    const int b = blk;

    uint64_t (&s_keys)[MKEYS] = sh.b.s_keys;
    uint64_t (&s_skeys)[MKEYS] = sh.b.s_skeys;
    float (&s_gm)[NGRP + 3] = sh.b.s_gm;
    uint64_t (&s_mask)[256 * MROW] = sh.b.s_mask;
    float4 (&s_boxo)[256] = sh.b.s_boxo;
    float4 (&s_braw)[256] = sh.b.s_braw;
    float (&s_areao)[256] = sh.b.s_areao;
    float4 (&s_keptbox)[TOPK] = sh.b.s_keptbox;
    uint64_t (&s_clsmask)[NCLS][4] = sh.b.s_clsmask;
    uint32_t (&s_ccount)[NCLS] = sh.b.s_ccount;
    uint32_t (&s_glist)[2048] = sh.b.s_glist;
    uint32_t (&s_wtot)[16] = sh.b.s_wtot;
    uint32_t (&s_shv)[12] = sh.b.s_shv;
    float (&s_bmaxarr)[16] = sh.b.s_bmaxarr;
    uint8_t (&s_clsl)[256] = sh.b.s_clsl;
    uint64_t (&s_K)[4] = sh.b.s_K;
    uint32_t* hist = (uint32_t*)s_keys;
    uint32_t* csum = (uint32_t*)s_skeys;

    // ---- init: zero hist + control
    for (int i = t; i < NBINS; i += 1024) hist[i] = 0;
    if (t < 12) s_shv[t] = 0;
    __syncthreads();

    // ---- load group maxes; >>13 histogram; box max
    {
        const float2* gmb = gm2 + (size_t)b * NGRP;
        float wm = 0.0f;
        for (int i = t; i < NGRP; i += 1024) {
            float2 v = gmb[i];
            s_gm[i] = v.x;
            wm = fmaxf(wm, v.y);
            if (v.x > CONF_T) {
                int ib = (int)((__float_as_uint(v.x) >> 13) - BASE13);
                ib = max(0, min(NBINS - 1, ib));
                atomicAdd(&hist[ib], 1u);
            }
        }
        #pragma unroll
        for (int m = 1; m < 64; m <<= 1) wm = fmaxf(wm, __shfl_xor(wm, m));
        if ((t & 63) == 0) s_bmaxarr[t >> 6] = wm;
    }
    __syncthreads();

    // ---- crossing via suffix scan over 1024 chunk-sums (8 bins/chunk)
    uint32_t v8 = 0;
    if (t * 8 < NBINS) {
        #pragma unroll
        for (int k = 0; k < 8; ++k) v8 += hist[t * 8 + k];
    }
    suffix_scan_1024(v8, t, s_wtot, csum);
    {
        uint32_t sIn = csum[t];
        uint32_t sNext = (t == 1023) ? 0u : csum[t + 1];
        if (sIn >= NSEL && sNext < NSEL) { s_shv[0] = (uint32_t)t; s_shv[1] = sNext; s_shv[2] = 1; }
    }
    __syncthreads();
    if (t == 0) {
        float mx = s_bmaxarr[0];
        #pragma unroll
        for (int k = 1; k < 16; ++k) mx = fmaxf(mx, s_bmaxarr[k]);
        sh.b.s_offm = mx + 1.0f;               // jnp.max(boxes) + 1
        if (s_shv[2]) {
            uint32_t chunk = s_shv[0], run2 = s_shv[1]; int cb = -1;
            for (int k = 7; k >= 0; --k) {
                uint32_t v = hist[chunk * 8 + k];
                if (cb < 0 && run2 + v >= NSEL) cb = (int)(chunk * 8 + k);
                run2 += v;
            }
            s_shv[3] = BASE13 + (uint32_t)cb;  // threshold in >>13 space
        } else s_shv[3] = 0;
    }
    __syncthreads();

    // ---- qualify groups ((gmax bits>>13) >= T13)
    const uint32_t T13 = s_shv[3];
    for (int i = t; i < NGRP; i += 1024) {
        float s = s_gm[i];
        if (s > CONF_T && (__float_as_uint(s) >> 13) >= T13) {
            uint32_t p = atomicAdd(&s_shv[8], 1u);
            if (p < 2048u) s_glist[p] = (uint32_t)i;
        }
    }
    __syncthreads();
    uint32_t ngl = s_shv[8]; if (ngl > 2048u) ngl = 2048u;

    // ---- gather candidate keys from qualified groups (hist dead)
    {
        const unsigned long long* kb = key64 + (size_t)b * NA;
        for (int idx = t; idx < (int)(ngl * 16); idx += 1024) {
            uint32_t gi = s_glist[idx >> 4];
            unsigned long long key = kb[gi * 16 + (idx & 15)];
            uint32_t bits = (uint32_t)(key >> 32);
            if (bits > CONF_BITS && (bits >> 13) >= T13) {
                uint32_t p = atomicAdd(&s_shv[4], 1u);
                if (p < MKEYS) s_keys[p] = key;
            }
        }
    }
    __syncthreads();
    uint32_t nGa = s_shv[4]; if (nGa > MKEYS) nGa = MKEYS;
    const int lim = (nGa < 256u) ? (int)nGa : 256;

    // ---- rank sort descending via readlane broadcast (guarded reads)
    {
        const int lane = t & 63;
        const uint32_t nch2 = (nGa + 63) >> 6;
        for (int s = 0; s < MKEYS / 1024; ++s) {
            int kid = t + s * 1024;
            bool act2 = kid < (int)nGa;
            if (__ballot(act2) == 0ull) continue;
            uint64_t my = act2 ? s_keys[kid] : ~0ull;
            uint32_t r = 0;
            for (uint32_t ch = 0; ch < nch2; ++ch) {
                uint32_t src = ch * 64 + (uint32_t)lane;
                uint64_t kc = (src < nGa) ? s_keys[src] : 0ull;
                uint32_t clo = (uint32_t)kc, chi = (uint32_t)(kc >> 32);
                for (int jj = 0; jj < 64; ++jj) {
                    uint32_t olo = (uint32_t)__builtin_amdgcn_readlane((int)clo, jj);
                    uint32_t ohi = (uint32_t)__builtin_amdgcn_readlane((int)chi, jj);
                    uint64_t ok = ((uint64_t)ohi << 32) | olo;
                    r += (ok > my) ? 1u : 0u;
                }
            }
            if (act2) s_skeys[r] = my;
        }
    }
    __syncthreads();

    // ---- prep first 256: box gather (1 line/cand), offset boxes, classes
    const float offm = sh.b.s_offm;
    if (t < 256) {
        if (t < lim) {
            uint64_t key = s_skeys[t];
            uint32_t low = (uint32_t)key;
            int c = (int)(low & 0x7Fu);
            uint32_t g = 0x1FFFFu - (low >> 7);
            s_clsl[t] = (uint8_t)c;
            float4 br = boxes[(size_t)b * NA + g];
            s_braw[t] = br;
            float off = (float)c * offm;
            float4 bo = make_float4(br.x + off, br.y + off, br.z + off, br.w + off);
            s_boxo[t] = bo;
            s_areao[t] = (bo.z - bo.x) * (bo.w - bo.y);
        } else {
            s_clsl[t] = 0;
            s_braw[t] = make_float4(0.f, 0.f, 0.f, 0.f);
            s_boxo[t] = make_float4(0.f, 0.f, 0.f, 0.f);
            s_areao[t] = 0.f;
        }
    }
    if (t < NCLS * 4) ((uint64_t*)s_clsmask)[t] = 0ull;
    __syncthreads();

    // ---- 256x256 suppression mask, register-resident via readlane
    {
        const int wv = t >> 6, lane = t & 63;
        const int rbase = (wv & 3) * 64, c = wv >> 2;
        const int i = rbase + lane;
        float4 bi = s_boxo[i];
        float aI = s_areao[i];
        float4 vj = s_boxo[c * 64 + lane];
        float vA = s_areao[c * 64 + lane];
        uint64_t m = 0ull;
        for (int jj = 0; jj < 64; ++jj) {
            float bx1 = rlf(vj.x, jj), by1 = rlf(vj.y, jj);
            float bx2 = rlf(vj.z, jj), by2 = rlf(vj.w, jj);
            float aJ  = rlf(vA, jj);
            float ix1 = fmaxf(bi.x, bx1), iy1 = fmaxf(bi.y, by1);
            float ix2 = fminf(bi.z, bx2), iy2 = fminf(bi.w, by2);
            float inter = fmaxf(ix2 - ix1, 0.f) * fmaxf(iy2 - iy1, 0.f);
            float uni = aI + aJ - inter;
            if (uni > 0.f && inter + inter > uni) m |= (1ull << jj);
        }
        s_mask[(size_t)i * MROW + c] = m;
    }
    __syncthreads();

    // ---- single-wave register Jacobi greedy NMS (exact fixpoint)
    if (t < 64) {
        const int lane = t;
        uint64_t mr[4][4];
        #pragma unroll
        for (int wr = 0; wr < 4; ++wr)
            #pragma unroll
            for (int wc = 0; wc < 4; ++wc)
                mr[wr][wc] = s_mask[(size_t)(wr * 64 + lane) * MROW + wc];
        const uint64_t below = (lane == 0) ? 0ull : ((~0ull) >> (64 - lane));
        uint64_t K[4];
        #pragma unroll
        for (int w = 0; w < 4; ++w) {
            int lo = w * 64, n = lim - lo;
            K[w] = (n >= 64) ? ~0ull : (n > 0 ? ((~0ull) >> (64 - n)) : 0ull);
        }
        for (int round = 0; round < 257; ++round) {
            uint64_t nK[4];
            #pragma unroll
            for (int wr = 0; wr < 4; ++wr) {
                uint64_t dead = 0ull;
                #pragma unroll
                for (int w = 0; w < 4; ++w) {
                    uint64_t mm = mr[wr][w] & K[w];
                    if (w < wr) dead |= mm;
                    else if (w == wr) dead |= (mm & below);
                }
                bool nb = (dead == 0ull) && (wr * 64 + lane < lim);
                nK[wr] = __ballot(nb);
            }
            bool same = (nK[0] == K[0]) && (nK[1] == K[1]) &&
                        (nK[2] == K[2]) && (nK[3] == K[3]);
            K[0] = nK[0]; K[1] = nK[1]; K[2] = nK[2]; K[3] = nK[3];
            if (same) break;
        }
        if (lane < 4) s_K[lane] = K[lane];
    }
    __syncthreads();

    // ---- per-class keep masks
    if (t < 256 && ((s_K[(t >> 6) & 3] >> (t & 63)) & 1ull))
        atomicOr(&s_clsmask[s_clsl[t]][(t >> 6) & 3], 1ull << (t & 63));
    __syncthreads();

    // ---- parallel output of first TOPK keeps (popcount order & slot)
    {
        const int jw = (t >> 6) & 3, jb = t & 63;
        bool kept = (t < 256) && ((s_K[jw] >> jb) & 1ull);
        if (kept) {
            const uint64_t below = (jb == 0) ? 0ull : ((~0ull) >> (64 - jb));
            uint32_t ord = (uint32_t)__popcll(s_K[jw] & below);
            for (int w = 0; w < jw; ++w) ord += (uint32_t)__popcll(s_K[w]);
            if (ord < TOPK) {
                int c = (int)s_clsl[t];
                const uint64_t* cm = s_clsmask[c];
                uint32_t slot = (uint32_t)__popcll(cm[jw] & below);
                for (int w = 0; w < jw; ++w) slot += (uint32_t)__popcll(cm[w]);
                float scv = __uint_as_float((uint32_t)(s_skeys[t] >> 32));
                float4 br = s_braw[t];
                float* o = out + (((size_t)b * (NCLS + 1) + (size_t)(c + 1)) * TOPK + slot) * 5;
                o[0] = scv; o[1] = br.x; o[2] = br.y; o[3] = br.z; o[4] = br.w;
                s_keptbox[ord] = s_boxo[t];
            }
        }
    }
    __syncthreads();

    // ---- t0 serial fallback past lim (exactness insurance; ~never taken)
    if (t == 0) {
        uint32_t nk = 0;
        #pragma unroll
        for (int w = 0; w < 4; ++w) nk += (uint32_t)__popcll(s_K[w]);
        if (nk < TOPK && nGa > (uint32_t)lim) {
            for (int c = 0; c < NCLS; ++c) {
                uint32_t n = 0;
                #pragma unroll
                for (int w = 0; w < 4; ++w) n += (uint32_t)__popcll(s_clsmask[c][w]);
                s_ccount[c] = n;
            }
            for (uint32_t ci = (uint32_t)lim; ci < nGa && nk < TOPK; ++ci) {
                uint64_t key = s_skeys[ci];
                uint32_t low = (uint32_t)key;
                int c = (int)(low & 0x7Fu);
                uint32_t g = 0x1FFFFu - (low >> 7);
                float4 br = boxes[(size_t)b * NA + g];
                float off = (float)c * offm;
                float4 bo = make_float4(br.x + off, br.y + off, br.z + off, br.w + off);
                float aB2 = (bo.z - bo.x) * (bo.w - bo.y);
                bool sup = false;
                for (uint32_t k2 = 0; k2 < nk && !sup; ++k2) {
                    float4 kb = s_keptbox[k2];
                    float aK = (kb.z - kb.x) * (kb.w - kb.y);
                    float ix1 = fmaxf(bo.x, kb.x), iy1 = fmaxf(bo.y, kb.y);
                    float ix2 = fminf(bo.z, kb.z), iy2 = fminf(bo.w, kb.w);
                    float inter = fmaxf(ix2 - ix1, 0.f) * fmaxf(iy2 - iy1, 0.f);
                    float uni = aB2 + aK - inter;
                    sup = (uni > 0.f && inter + inter > uni);
                }
                if (!sup) {
                    uint32_t slot = s_ccount[c]; s_ccount[c] = slot + 1;
                    float scv = __uint_as_float((uint32_t)(key >> 32));
                    float* o = out + (((size_t)b * (NCLS + 1) + (size_t)(c + 1)) * TOPK + slot) * 5;
                    o[0] = scv; o[1] = br.x; o[2] = br.y; o[3] = br.z; o[4] = br.w;
                    s_keptbox[nk] = bo;
                    ++nk;
                }
            }
        }
    }
}

extern "C" void kernel_launch(void* const* d_in, const int* in_sizes, int n_in,
                              void* d_out, int out_size, void* d_ws, size_t ws_size,
                              hipStream_t stream)
{
    const float* conf = (const float*)d_in[0];   // [B, A, 81] f32
    const float* reg  = (const float*)d_in[1];   // [B, A, 4]  f32
    const float* anch = (const float*)d_in[2];   // [A, 4]     f32
    float* out = (float*)d_out;                  // [B, 81, 200, 5] f32

    char* ws = (char*)d_ws;
    unsigned long long* key64 = (unsigned long long*)ws;               // NB*NA u64
    float4* boxes = (float4*)(ws + (size_t)NB * NA * 8);               // NB*NA float4
    float2* gm2 = (float2*)(ws + (size_t)NB * NA * 24);                // NB*NGRP float2

    void* args[] = { (void*)&conf, (void*)&reg, (void*)&anch,
                     (void*)&key64, (void*)&boxes, (void*)&gm2, (void*)&out };
    hipLaunchCooperativeKernel((const void*)fused_kernel, dim3(NBLKS), dim3(1024),
                               args, 0, stream);
}

// Round 18
// 63.566 us; speedup vs baseline: 1.7848x; 1.7848x over previous
//
#include <hip/hip_runtime.h>
#include <stdint.h>

#define NCLS 80
#define TOPK 200
#define CONF_T 0.05f
#define CONF_BITS 0x3D4CCCCDu  // __float_as_uint(0.05f)
#define TFIX 0.9775f            // spec-emission threshold (exact fallback below)
#define CROPF 300.0f
#define NA 49104
#define NB 8
#define NSEL 256
#define MKEYS 4096
#define APB 64
#define T1 256
#define CHUNK (APB * 81)
#define NGRP (NA / 16)          // 3069 16-anchor groups per image
#define MROW 5                  // mask row stride in u64
#define OUTFLO ((NCLS + 1) * TOPK * 5)   // 81000 floats per image
#define NBLK1 ((NB * NA) / APB)          // 6138 phase1 blocks
#define BASE13 125542u          // CONF_BITS >> 13
#define NBINS 4512              // covers (0.05, 1.0] in >>13 space

__device__ __forceinline__ void decode_box(const float4 rg, const float4 an,
                                           float& x1, float& y1, float& x2, float& y2) {
    // anchors: (ymin, xmin, ymax, xmax); reg: (dy, dx, dh, dw)
    float yca = (an.x + an.z) * 0.5f;
    float xca = (an.y + an.w) * 0.5f;
    float ha = an.z - an.x;
    float wa = an.w - an.y;
    float w = expf(rg.w) * wa;
    float h = expf(rg.z) * ha;
    float yc = rg.x * ha + yca;
    float xc = rg.y * wa + xca;
    x1 = fmaxf(xc - w * 0.5f, 0.0f) / CROPF;
    y1 = fmaxf(yc - h * 0.5f, 0.0f) / CROPF;
    x2 = fminf(xc + w * 0.5f, CROPF - 1.0f) / CROPF;
    y2 = fminf(yc + h * 0.5f, CROPF - 1.0f) / CROPF;
}

__device__ __forceinline__ float rlf(float v, int l) {
    return __int_as_float(__builtin_amdgcn_readlane(__float_as_int(v), l));
}

// Phase 1 (r12 base + atomic-free spec emission): conf -> key64 + boxes;
// per-group float4{smax, boxmax, count(score>=TFIX), 0}; qualifying keys
// compact-written to the group's private 16-slot region (one writer per group).
__global__ __launch_bounds__(T1) void phase1_kernel(
    const float* __restrict__ conf, const float* __restrict__ reg,
    const float* __restrict__ anch, unsigned long long* __restrict__ key64,
    float4* __restrict__ boxes, float4* __restrict__ gmi,
    unsigned long long* __restrict__ speclist, float* __restrict__ outz)
{
    __shared__ float lds[CHUNK];
    const int blk = blockIdx.x, t = threadIdx.x;

    // ---- stripe-zero d_out (2.6MB over 1.57M threads -> <=1 float4 store each)
    {
        const int gid = blk * T1 + t;
        constexpr int TOT4 = NB * OUTFLO / 4;      // 162000 float4s
        if (gid < TOT4)
            reinterpret_cast<float4*>(outz)[gid] = make_float4(0.f, 0.f, 0.f, 0.f);
    }

    const float4* src = reinterpret_cast<const float4*>(conf + (size_t)blk * CHUNK);
    float4* dst = reinterpret_cast<float4*>(lds);
    for (int i = t; i < CHUNK / 4; i += T1) dst[i] = src[i];
    __syncthreads();

    const int la = t >> 2, sub = t & 3;
    const int quad = blk * APB + la;           // global anchor b*NA + a
    const float* crow = lds + la * 81;
    float best = -3.0e38f; int bc = 255;
    #pragma unroll
    for (int k = 0; k < 20; ++k) {             // lane sub: classes 1+sub, +4 each
        int c = 1 + sub + 4 * k;
        float v = crow[c];
        if (v > best) { best = v; bc = c; }    // strict > : first-index tie-break
    }
    for (int m = 1; m <= 2; m <<= 1) {
        float ov = __shfl_xor(best, m);
        int oc = __shfl_xor(bc, m);
        if (ov > best || (ov == best && oc < bc)) { best = ov; bc = oc; }
    }
    unsigned long long key = 0ull;
    float bmaxl = 0.0f, sflt = -1.0f;
    if (sub == 0) {
        int a = quad % NA;
        sflt = 1.0f / (1.0f + expf(-best));
        uint32_t ginv = 0x1FFFFu - (uint32_t)a; // preserves smaller-index tie-break
        key = ((unsigned long long)__float_as_uint(sflt) << 32)
            | (unsigned long long)((ginv << 7) | (uint32_t)(bc - 1));
        float4 rg = reinterpret_cast<const float4*>(reg)[quad];
        float4 an = reinterpret_cast<const float4*>(anch)[a];
        float x1, y1, x2, y2; decode_box(rg, an, x1, y1, x2, y2);
        boxes[quad] = make_float4(x1, y1, x2, y2);
        bmaxl = fmaxf(fmaxf(x1, y1), fmaxf(x2, y2));
    }
    // compact key stores: lane l<16 takes lane 4l's key -> contiguous 128B/wave
    {
        const int lane = t & 63, w = t >> 6;
        unsigned long long kk = __shfl(key, (lane & 15) * 4);
        if (lane < 16)
            key64[(size_t)blk * APB + w * 16 + lane] = kk;
    }
    // spec emission: each wave == one 16-anchor group; single writer, no atomics
    uint32_t gcnt;
    {
        const int lane = t & 63;
        bool qual = (sub == 0) && (sflt >= TFIX);
        uint64_t qm = __ballot(qual);
        gcnt = (uint32_t)__popcll(qm);
        if (qual) {
            uint32_t rank = (uint32_t)__popcll(qm & ((1ull << lane) - 1ull));
            speclist[(size_t)(blk * 4 + (t >> 6)) * 16 + rank] = key;
        }
    }
    float wbest = best;
    #pragma unroll
    for (int m = 1; m < 64; m <<= 1) {
        wbest = fmaxf(wbest, __shfl_xor(wbest, m));
        bmaxl = fmaxf(bmaxl, __shfl_xor(bmaxl, m));
    }
    if ((t & 63) == 0)
        gmi[blk * 4 + (t >> 6)] = make_float4(1.0f / (1.0f + expf(-wbest)), bmaxl,
                                              __uint_as_float(gcnt), 0.0f);
}

// block-wide inclusive SUFFIX scan over 1024 values; result into outarr[t].
__device__ __forceinline__ void suffix_scan_1024(uint32_t v, int t,
                                                 uint32_t* wtot, uint32_t* outarr) {
    uint32_t r = v;
    const int lane = t & 63, w = t >> 6;
    #pragma unroll
    for (int m = 1; m < 64; m <<= 1) {
        uint32_t o = __shfl_down(r, m);
        if (lane + m < 64) r += o;
    }
    if (lane == 0) wtot[w] = r;
    __syncthreads();
    if (t < 16) {
        uint32_t v0 = wtot[t], x = v0;
        #pragma unroll
        for (int m = 1; m < 16; m <<= 1) {
            uint32_t o = __shfl_down(x, m);
            if (t + m < 16) x += o;
        }
        wtot[t] = x - v0;                      // exclusive suffix of wave totals
    }
    __syncthreads();
    outarr[t] = r + wtot[w];
    __syncthreads();
}

// Phase 2: FAST path (expected) = scan spec counts, copy pre-compacted keys
// (no hist/threshold-scan/qualify/gather). SLOW path (total<NSEL or >MKEYS;
// exactness insurance) = r12-validated >>13 select. Then validated sort /
// mask / register-Jacobi / popcount-output machinery (r12 verbatim).
__global__ __launch_bounds__(1024) void phase2_kernel(
    const unsigned long long* __restrict__ key64, const float4* __restrict__ boxes,
    const float4* __restrict__ gmi, const unsigned long long* __restrict__ speclist,
    float* __restrict__ out)
{
    __shared__ uint64_t s_keys[MKEYS];        // 32KB  alias: hist u32[NBINS] (slow)
    __shared__ uint64_t s_skeys[MKEYS];       // 32KB  alias: csum u32[1024]
    __shared__ float    s_gm[NGRP + 3];       // 12KB group score maxes (slow path)
    __shared__ uint64_t s_mask[256 * MROW];   // 10KB
    __shared__ float4   s_boxo[256];
    __shared__ float4   s_braw[256];
    __shared__ float    s_areao[256];
    __shared__ float4   s_keptbox[TOPK];
    __shared__ uint64_t s_clsmask[NCLS][4];
    __shared__ uint32_t s_ccount[NCLS];
    __shared__ uint32_t s_glist[2048];        // 8KB (slow path)
    __shared__ uint32_t s_wtot[16];
    __shared__ uint32_t s_shv[12];
    __shared__ float    s_bmaxarr[16];
    __shared__ float    s_offm;
    __shared__ uint8_t  s_clsl[256];
    __shared__ uint64_t s_K[4];

    uint32_t* hist = (uint32_t*)s_keys;
    uint32_t* csum = (uint32_t*)s_skeys;

    const int b = blockIdx.x;
    const int t = threadIdx.x;

    // ---- B1: zero control
    if (t < 12) s_shv[t] = 0;
    __syncthreads();

    // ---- B2: load group metas; stage s_gm (slow-path insurance); counts in regs
    uint32_t c0 = 0, c1 = 0, c2 = 0;
    {
        const float4* gmb = gmi + (size_t)b * NGRP;
        float wm = 0.0f;
        int k = 0;
        for (int i = t; i < NGRP; i += 1024, ++k) {
            float4 v = gmb[i];
            s_gm[i] = v.x;
            wm = fmaxf(wm, v.y);
            uint32_t c = __float_as_uint(v.z);
            if (k == 0) c0 = c; else if (k == 1) c1 = c; else c2 = c;
        }
        #pragma unroll
        for (int m = 1; m < 64; m <<= 1) wm = fmaxf(wm, __shfl_xor(wm, m));
        if ((t & 63) == 0) s_bmaxarr[t >> 6] = wm;
    }
    // scan spec counts (3 groups/thread)
    suffix_scan_1024(c0 + c1 + c2, t, s_wtot, csum);
    const uint32_t mysuf = csum[t];
    const uint32_t total = csum[0];            // inclusive suffix at t=0
    if (t == 0) {
        float mx = s_bmaxarr[0];
        #pragma unroll
        for (int k = 1; k < 16; ++k) mx = fmaxf(mx, s_bmaxarr[k]);
        s_offm = mx + 1.0f;                    // jnp.max(boxes) + 1
        s_shv[5] = (total >= NSEL && total <= MKEYS) ? 1u : 0u;
        s_shv[4] = total;
    }
    __syncthreads();

    const bool fastp = (s_shv[5] != 0);        // uniform
    if (fastp) {
        // ---- FAST: copy pre-compacted keys (no atomics, no hist)
        const unsigned long long* sp = speclist + (size_t)b * NA;   // NGRP*16 == NA
        uint32_t p = total - mysuf;            // this thread's region start
        for (uint32_t j = 0; j < c0; ++j) s_keys[p++] = sp[(size_t)t * 16 + j];
        for (uint32_t j = 0; j < c1; ++j) s_keys[p++] = sp[(size_t)(t + 1024) * 16 + j];
        for (uint32_t j = 0; j < c2; ++j) s_keys[p++] = sp[(size_t)(t + 2048) * 16 + j];
        __syncthreads();
    } else {
        // ---- SLOW (r12-validated >>13 select; exactness insurance)
        for (int i = t; i < NBINS; i += 1024) hist[i] = 0;
        if (t == 0) s_shv[4] = 0;              // reset gather counter
        __syncthreads();
        for (int i = t; i < NGRP; i += 1024) {
            float s = s_gm[i];
            if (s > CONF_T) {
                int ib = (int)((__float_as_uint(s) >> 13) - BASE13);
                ib = max(0, min(NBINS - 1, ib));
                atomicAdd(&hist[ib], 1u);
            }
        }
        __syncthreads();
        uint32_t v8 = 0;
        if (t * 8 < NBINS) {
            #pragma unroll
            for (int k = 0; k < 8; ++k) v8 += hist[t * 8 + k];
        }
        suffix_scan_1024(v8, t, s_wtot, csum);
        {
            uint32_t sIn = csum[t];
            uint32_t sNext = (t == 1023) ? 0u : csum[t + 1];
            if (sIn >= NSEL && sNext < NSEL) { s_shv[0] = (uint32_t)t; s_shv[1] = sNext; s_shv[2] = 1; }
        }
        __syncthreads();
        if (t == 0) {
            if (s_shv[2]) {
                uint32_t chunk = s_shv[0], run2 = s_shv[1]; int cb = -1;
                for (int k = 7; k >= 0; --k) {
                    uint32_t v = hist[chunk * 8 + k];
                    if (cb < 0 && run2 + v >= NSEL) cb = (int)(chunk * 8 + k);
                    run2 += v;
                }
                s_shv[3] = BASE13 + (uint32_t)cb;
            } else s_shv[3] = 0;
        }
        __syncthreads();
        const uint32_t T13 = s_shv[3];
        for (int i = t; i < NGRP; i += 1024) {
            float s = s_gm[i];
            if (s > CONF_T && (__float_as_uint(s) >> 13) >= T13) {
                uint32_t p = atomicAdd(&s_shv[8], 1u);
                if (p < 2048u) s_glist[p] = (uint32_t)i;
            }
        }
        __syncthreads();
        uint32_t ngl = s_shv[8]; if (ngl > 2048u) ngl = 2048u;
        {
            const unsigned long long* kb = key64 + (size_t)b * NA;
            for (int idx = t; idx < (int)(ngl * 16); idx += 1024) {
                uint32_t gi = s_glist[idx >> 4];
                unsigned long long key = kb[gi * 16 + (idx & 15)];
                uint32_t bits = (uint32_t)(key >> 32);
                if (bits > CONF_BITS && (bits >> 13) >= T13) {
                    uint32_t p = atomicAdd(&s_shv[4], 1u);
                    if (p < MKEYS) s_keys[p] = key;
                }
            }
        }
        __syncthreads();
    }
    uint32_t nGa = s_shv[4]; if (nGa > MKEYS) nGa = MKEYS;
    const int lim = (nGa < 256u) ? (int)nGa : 256;

    // ---- rank sort descending via readlane broadcast (guarded reads)
    {
        const int lane = t & 63;
        const uint32_t nch = (nGa + 63) >> 6;
        for (int s = 0; s < MKEYS / 1024; ++s) {
            int kid = t + s * 1024;
            bool act = kid < (int)nGa;
            if (__ballot(act) == 0ull) continue;
            uint64_t my = act ? s_keys[kid] : ~0ull;
            uint32_t r = 0;
            for (uint32_t ch = 0; ch < nch; ++ch) {
                uint32_t src = ch * 64 + (uint32_t)lane;
                uint64_t kc = (src < nGa) ? s_keys[src] : 0ull;
                uint32_t clo = (uint32_t)kc, chi = (uint32_t)(kc >> 32);
                for (int jj = 0; jj < 64; ++jj) {
                    uint32_t olo = (uint32_t)__builtin_amdgcn_readlane((int)clo, jj);
                    uint32_t ohi = (uint32_t)__builtin_amdgcn_readlane((int)chi, jj);
                    uint64_t ok = ((uint64_t)ohi << 32) | olo;
                    r += (ok > my) ? 1u : 0u;
                }
            }
            if (act) s_skeys[r] = my;
        }
    }
    __syncthreads();

    // ---- prep first 256: box gather (1 line/cand), offset boxes, classes
    const float offm = s_offm;
    if (t < 256) {
        if (t < lim) {
            uint64_t key = s_skeys[t];
            uint32_t low = (uint32_t)key;
            int c = (int)(low & 0x7Fu);
            uint32_t g = 0x1FFFFu - (low >> 7);
            s_clsl[t] = (uint8_t)c;
            float4 br = boxes[(size_t)b * NA + g];
            s_braw[t] = br;
            float off = (float)c * offm;
            float4 bo = make_float4(br.x + off, br.y + off, br.z + off, br.w + off);
            s_boxo[t] = bo;
            s_areao[t] = (bo.z - bo.x) * (bo.w - bo.y);
        } else {
            s_clsl[t] = 0;
            s_braw[t] = make_float4(0.f, 0.f, 0.f, 0.f);
            s_boxo[t] = make_float4(0.f, 0.f, 0.f, 0.f);
            s_areao[t] = 0.f;
        }
    }
    if (t < NCLS * 4) ((uint64_t*)s_clsmask)[t] = 0ull;
    __syncthreads();

    // ---- 256x256 suppression mask, register-resident via readlane
    {
        const int wv = t >> 6, lane = t & 63;
        const int rbase = (wv & 3) * 64, c = wv >> 2;
        const int i = rbase + lane;
        float4 bi = s_boxo[i];
        float aI = s_areao[i];
        float4 vj = s_boxo[c * 64 + lane];
        float vA = s_areao[c * 64 + lane];
        uint64_t m = 0ull;
        for (int jj = 0; jj < 64; ++jj) {
            float bx1 = rlf(vj.x, jj), by1 = rlf(vj.y, jj);
            float bx2 = rlf(vj.z, jj), by2 = rlf(vj.w, jj);
            float aJ  = rlf(vA, jj);
            float ix1 = fmaxf(bi.x, bx1), iy1 = fmaxf(bi.y, by1);
            float ix2 = fminf(bi.z, bx2), iy2 = fminf(bi.w, by2);
            float inter = fmaxf(ix2 - ix1, 0.f) * fmaxf(iy2 - iy1, 0.f);
            float uni = aI + aJ - inter;
            if (uni > 0.f && inter + inter > uni) m |= (1ull << jj);
        }
        s_mask[(size_t)i * MROW + c] = m;
    }
    __syncthreads();

    // ---- single-wave register Jacobi greedy NMS (exact fixpoint; no barriers)
    if (t < 64) {
        const int lane = t;
        uint64_t mr[4][4];
        #pragma unroll
        for (int wr = 0; wr < 4; ++wr)
            #pragma unroll
            for (int wc = 0; wc < 4; ++wc)
                mr[wr][wc] = s_mask[(size_t)(wr * 64 + lane) * MROW + wc];
        const uint64_t below = (lane == 0) ? 0ull : ((~0ull) >> (64 - lane));
        uint64_t K[4];
        #pragma unroll
        for (int w = 0; w < 4; ++w) {
            int lo = w * 64, n = lim - lo;
            K[w] = (n >= 64) ? ~0ull : (n > 0 ? ((~0ull) >> (64 - n)) : 0ull);
        }
        for (int round = 0; round < 257; ++round) {
            uint64_t nK[4];
            #pragma unroll
            for (int wr = 0; wr < 4; ++wr) {
                uint64_t dead = 0ull;
                #pragma unroll
                for (int w = 0; w < 4; ++w) {
                    uint64_t mm = mr[wr][w] & K[w];
                    if (w < wr) dead |= mm;
                    else if (w == wr) dead |= (mm & below);
                }
                bool nb = (dead == 0ull) && (wr * 64 + lane < lim);
                nK[wr] = __ballot(nb);
            }
            bool same = (nK[0] == K[0]) && (nK[1] == K[1]) &&
                        (nK[2] == K[2]) && (nK[3] == K[3]);
            K[0] = nK[0]; K[1] = nK[1]; K[2] = nK[2]; K[3] = nK[3];
            if (same) break;
        }
        if (lane < 4) s_K[lane] = K[lane];
    }
    __syncthreads();

    // ---- per-class keep masks
    if (t < 256 && ((s_K[(t >> 6) & 3] >> (t & 63)) & 1ull))
        atomicOr(&s_clsmask[s_clsl[t]][(t >> 6) & 3], 1ull << (t & 63));
    __syncthreads();

    // ---- parallel output of first TOPK keeps (popcount order & slot)
    {
        const int jw = (t >> 6) & 3, jb = t & 63;
        bool kept = (t < 256) && ((s_K[jw] >> jb) & 1ull);
        if (kept) {
            const uint64_t below = (jb == 0) ? 0ull : ((~0ull) >> (64 - jb));
            uint32_t ord = (uint32_t)__popcll(s_K[jw] & below);
            for (int w = 0; w < jw; ++w) ord += (uint32_t)__popcll(s_K[w]);
            if (ord < TOPK) {
                int c = (int)s_clsl[t];
                const uint64_t* cm = s_clsmask[c];
                uint32_t slot = (uint32_t)__popcll(cm[jw] & below);
                for (int w = 0; w < jw; ++w) slot += (uint32_t)__popcll(cm[w]);
                float scv = __uint_as_float((uint32_t)(s_skeys[t] >> 32));
                float4 br = s_braw[t];
                float* o = out + (((size_t)b * (NCLS + 1) + (size_t)(c + 1)) * TOPK + slot) * 5;
                o[0] = scv; o[1] = br.x; o[2] = br.y; o[3] = br.z; o[4] = br.w;
                s_keptbox[ord] = s_boxo[t];
            }
        }
    }
    __syncthreads();

    // ---- t0 serial fallback past lim (exactness insurance; ~never taken)
    if (t == 0) {
        uint32_t nk = 0;
        #pragma unroll
        for (int w = 0; w < 4; ++w) nk += (uint32_t)__popcll(s_K[w]);
        if (nk < TOPK && nGa > (uint32_t)lim) {
            for (int c = 0; c < NCLS; ++c) {
                uint32_t n = 0;
                #pragma unroll
                for (int w = 0; w < 4; ++w) n += (uint32_t)__popcll(s_clsmask[c][w]);
                s_ccount[c] = n;
            }
            for (uint32_t ci = (uint32_t)lim; ci < nGa && nk < TOPK; ++ci) {
                uint64_t key = s_skeys[ci];
                uint32_t low = (uint32_t)key;
                int c = (int)(low & 0x7Fu);
                uint32_t g = 0x1FFFFu - (low >> 7);
                float4 br = boxes[(size_t)b * NA + g];
                float off = (float)c * offm;
                float4 bo = make_float4(br.x + off, br.y + off, br.z + off, br.w + off);
                float aB2 = (bo.z - bo.x) * (bo.w - bo.y);
                bool sup = false;
                for (uint32_t k2 = 0; k2 < nk && !sup; ++k2) {
                    float4 kb = s_keptbox[k2];
                    float aK = (kb.z - kb.x) * (kb.w - kb.y);
                    float ix1 = fmaxf(bo.x, kb.x), iy1 = fmaxf(bo.y, kb.y);
                    float ix2 = fminf(bo.z, kb.z), iy2 = fminf(bo.w, kb.w);
                    float inter = fmaxf(ix2 - ix1, 0.f) * fmaxf(iy2 - iy1, 0.f);
                    float uni = aB2 + aK - inter;
                    sup = (uni > 0.f && inter + inter > uni);
                }
                if (!sup) {
                    uint32_t slot = s_ccount[c]; s_ccount[c] = slot + 1;
                    float scv = __uint_as_float((uint32_t)(key >> 32));
                    float* o = out + (((size_t)b * (NCLS + 1) + (size_t)(c + 1)) * TOPK + slot) * 5;
                    o[0] = scv; o[1] = br.x; o[2] = br.y; o[3] = br.z; o[4] = br.w;
                    s_keptbox[nk] = bo;
                    ++nk;
                }
            }
        }
    }
}

extern "C" void kernel_launch(void* const* d_in, const int* in_sizes, int n_in,
                              void* d_out, int out_size, void* d_ws, size_t ws_size,
                              hipStream_t stream)
{
    const float* conf = (const float*)d_in[0];   // [B, A, 81] f32
    const float* reg  = (const float*)d_in[1];   // [B, A, 4]  f32
    const float* anch = (const float*)d_in[2];   // [A, 4]     f32
    float* out = (float*)d_out;                  // [B, 81, 200, 5] f32

    char* ws = (char*)d_ws;
    unsigned long long* key64 = (unsigned long long*)ws;               // NB*NA u64
    float4* boxes = (float4*)(ws + (size_t)NB * NA * 8);               // NB*NA float4
    float4* gmi   = (float4*)(ws + (size_t)NB * NA * 24);              // NB*NGRP float4
    unsigned long long* speclist =
        (unsigned long long*)(ws + (size_t)NB * NA * 24
                                 + (size_t)NB * NGRP * 16);            // NB*NA u64

    phase1_kernel<<<NBLK1, T1, 0, stream>>>(conf, reg, anch, key64, boxes,
                                            gmi, speclist, out);
    phase2_kernel<<<NB, 1024, 0, stream>>>(key64, boxes, gmi, speclist, out);
}